// Round 1
// baseline (569.271 us; speedup 1.0000x reference)
//
#include <hip/hip_runtime.h>
#include <math.h>

// EnergyCoulomb: B=32, N=512, D=1024, H=512
// Phase 1: fused 2-layer MLP (both energy net and charge net) as one tiled
//          fp32 GEMM [16384 x 1024] x [1024 x 512(x2)] with ssp+W2-dot epilogue,
//          producing per-atom yi_part and q_part (pre-bias2) via atomics.
// Phase 2: per-batch pairwise Coulomb sum + masked y-sum -> out[32].

#define BM 128
#define BN 64
#define BK 16

__device__ __forceinline__ float ssp_f(float x) {
    // softplus(x) - ln2, numerically stable
    return fmaxf(x, 0.0f) + log1pf(expf(-fabsf(x))) - 0.6931471805599453f;
}

__global__ __launch_bounds__(256) void mlp_gemm(
    const float* __restrict__ A,    // [16384,1024] representation
    const float* __restrict__ W1,   // [1024,512]
    const float* __restrict__ Wc1,  // [1024,512]
    const float* __restrict__ b1,
    const float* __restrict__ bc1,
    const float* __restrict__ W2,   // [512]
    const float* __restrict__ Wc2,  // [512]
    float* __restrict__ yi_part,    // [16384] (no +b2 yet)
    float* __restrict__ q_part)     // [16384] (no +bc2 yet)
{
    const int K = 1024;
    const int bm = blockIdx.x;            // 128 row tiles of 128 rows
    const int bn = blockIdx.y;            // 16 col tiles: 0..7 -> W1, 8..15 -> Wc1
    const bool is_q = (bn >= 8);
    const float* __restrict__ W = is_q ? Wc1 : W1;
    const int j0 = (bn & 7) * BN;         // column offset within the 512-wide half

    __shared__ float As[BK][BM + 4];      // row length 132 floats = 33*16B (aligned)
    __shared__ float Bs[BK][BN + 4];      // row length 68 floats = 17*16B (aligned)
    __shared__ float red[BM];

    const int tid = threadIdx.x;          // 256
    const int tx = tid & 15;              // col group (4 cols)
    const int ty = tid >> 4;              // row group (8 rows)

    float acc[8][4];
#pragma unroll
    for (int r = 0; r < 8; r++)
#pragma unroll
        for (int c = 0; c < 4; c++) acc[r][c] = 0.0f;

    // global load mapping
    const int a_row = tid >> 2;           // 0..63 (and +64)
    const int a_k4  = (tid & 3) * 4;      // 0,4,8,12
    const float* Arow0 = A + (size_t)(bm * BM + a_row) * K;
    const float* Arow1 = Arow0 + (size_t)64 * K;
    const int w_k = tid >> 4;             // 0..15
    const int w_j = (tid & 15) * 4;       // 0..60

    for (int kt = 0; kt < K; kt += BK) {
        float4 av0 = *(const float4*)(Arow0 + kt + a_k4);
        float4 av1 = *(const float4*)(Arow1 + kt + a_k4);
        float4 wv  = *(const float4*)(W + (size_t)(kt + w_k) * 512 + j0 + w_j);
        __syncthreads();  // previous iteration's reads complete before overwrite
        As[a_k4 + 0][a_row] = av0.x;
        As[a_k4 + 1][a_row] = av0.y;
        As[a_k4 + 2][a_row] = av0.z;
        As[a_k4 + 3][a_row] = av0.w;
        As[a_k4 + 0][a_row + 64] = av1.x;
        As[a_k4 + 1][a_row + 64] = av1.y;
        As[a_k4 + 2][a_row + 64] = av1.z;
        As[a_k4 + 3][a_row + 64] = av1.w;
        *(float4*)&Bs[w_k][w_j] = wv;
        __syncthreads();
#pragma unroll
        for (int kk = 0; kk < BK; kk++) {
            float4 a0 = *(const float4*)&As[kk][ty * 8];
            float4 a1 = *(const float4*)&As[kk][ty * 8 + 4];
            float4 bv = *(const float4*)&Bs[kk][tx * 4];
            float ar[8] = {a0.x, a0.y, a0.z, a0.w, a1.x, a1.y, a1.z, a1.w};
            float bc[4] = {bv.x, bv.y, bv.z, bv.w};
#pragma unroll
            for (int r = 0; r < 8; r++)
#pragma unroll
                for (int c = 0; c < 4; c++)
                    acc[r][c] = fmaf(ar[r], bc[c], acc[r][c]);
        }
    }

    // epilogue: per row, sum_c v[j]*ssp(acc + bias[j]); reduce over tx; atomicAdd
    const float* bb = is_q ? bc1 : b1;
    const float* vv = is_q ? Wc2 : W2;
    float bias[4], v[4];
#pragma unroll
    for (int c = 0; c < 4; c++) {
        bias[c] = bb[j0 + tx * 4 + c];
        v[c]    = vv[j0 + tx * 4 + c];
    }
    if (tid < BM) red[tid] = 0.0f;
    __syncthreads();
#pragma unroll
    for (int r = 0; r < 8; r++) {
        float s = 0.0f;
#pragma unroll
        for (int c = 0; c < 4; c++)
            s += v[c] * ssp_f(acc[r][c] + bias[c]);
        atomicAdd(&red[ty * 8 + r], s);
    }
    __syncthreads();
    float* target = is_q ? q_part : yi_part;
    if (tid < BM) atomicAdd(&target[(size_t)bm * BM + tid], red[tid]);
}

__global__ __launch_bounds__(256) void coulomb_k(
    const float* __restrict__ R,        // [32,512,3]
    const float* __restrict__ mask,     // [32,512]
    const float* __restrict__ yi_part,  // [32*512]
    const float* __restrict__ q_part,   // [32*512]
    const float* __restrict__ b2p,
    const float* __restrict__ bc2p,
    float* __restrict__ out)            // [32]
{
    const int N = 512;
    const int b = blockIdx.y;
    const int chunk = blockIdx.x;       // 8 chunks x 64 i's
    __shared__ float Rx[512], Ry[512], Rz[512], QM[512];
    __shared__ float rbuf[4];
    const int tid = threadIdx.x;
    const float bc2 = bc2p[0];
    const float b2 = b2p[0];

    for (int j = tid; j < N; j += 256) {
        float m = mask[b * N + j];
        const float* rp = R + ((size_t)b * N + j) * 3;
        Rx[j] = rp[0];
        Ry[j] = rp[1];
        Rz[j] = rp[2];
        QM[j] = (q_part[b * N + j] + bc2) * m;   // q_j * mask_j
    }
    __syncthreads();

    const int i = chunk * 64 + (tid & 63);
    const int js = (tid >> 6) * 128;    // 4 j-slices of 128
    const float xi = Rx[i], yi = Ry[i], zi = Rz[i], qmi = QM[i];
    float e = 0.0f;
    for (int j = js; j < js + 128; j++) {
        float dx = xi - Rx[j];
        float dy = yi - Ry[j];
        float dz = zi - Rz[j];
        float d2 = dx * dx + dy * dy + dz * dz;
        float dist = sqrtf(d2);         // d2>0 always off-diagonal; diag excluded below
        float t = 1e-5f + dist;
        float term = qmi * QM[j] / (t * t);
        e += (j == i) ? 0.0f : term;
    }
    // y contribution (once per i; wave 0 covers all 64 i's of this chunk)
    if (tid < 64) {
        int ii = chunk * 64 + tid;
        e += (yi_part[b * N + ii] + b2) * mask[b * N + ii];
    }
    // reduce 256 threads -> 1
    for (int off = 32; off > 0; off >>= 1) e += __shfl_down(e, off, 64);
    if ((tid & 63) == 0) rbuf[tid >> 6] = e;
    __syncthreads();
    if (tid == 0) atomicAdd(&out[b], rbuf[0] + rbuf[1] + rbuf[2] + rbuf[3]);
}

extern "C" void kernel_launch(void* const* d_in, const int* in_sizes, int n_in,
                              void* d_out, int out_size, void* d_ws, size_t ws_size,
                              hipStream_t stream) {
    const float* rep  = (const float*)d_in[0];
    const float* R    = (const float*)d_in[1];
    const float* mask = (const float*)d_in[2];
    const float* W1   = (const float*)d_in[3];
    const float* b1   = (const float*)d_in[4];
    const float* W2   = (const float*)d_in[5];
    const float* b2   = (const float*)d_in[6];
    const float* Wc1  = (const float*)d_in[7];
    const float* bc1  = (const float*)d_in[8];
    const float* Wc2  = (const float*)d_in[9];
    const float* bc2  = (const float*)d_in[10];
    float* out = (float*)d_out;

    float* yi_part = (float*)d_ws;
    float* q_part  = yi_part + 16384;

    hipMemsetAsync(d_ws, 0, 2 * 16384 * sizeof(float), stream);
    hipMemsetAsync(d_out, 0, 32 * sizeof(float), stream);

    mlp_gemm<<<dim3(128, 16), 256, 0, stream>>>(rep, W1, Wc1, b1, bc1, W2, Wc2,
                                                yi_part, q_part);
    coulomb_k<<<dim3(8, 32), 256, 0, stream>>>(R, mask, yi_part, q_part, b2, bc2, out);
}

// Round 2
// 190.894 us; speedup vs baseline: 2.9821x; 2.9821x over previous
//
#include <hip/hip_runtime.h>
#include <math.h>

// EnergyCoulomb: B=32, N=512, D=1024, H=512
// R2: bf16 MFMA GEMM (m97-style) for the fused 2-layer MLPs.
//   conv_a: rep fp32 -> bf16 [16384,1024]
//   conv_w: W1||Wc1 fp32 -> bf16 transposed to Bt [n=1024][k=1024]
//   gemm_mfma: [16384x1024]x[1024x1024] bf16, 128x128 tile, BK=32,
//              global_load_lds(16B) staging with XOR k-chunk swizzle,
//              ssp + W2-dot epilogue -> yi_part/q_part via atomics
//   coulomb_k: pairwise Coulomb + masked y-sum -> out[32]

typedef unsigned short u16;
typedef unsigned int u32;
typedef __bf16 bf16x8 __attribute__((ext_vector_type(8)));
typedef float f32x4 __attribute__((ext_vector_type(4)));

#define GK 1024

#define GLOAD_LDS16(g, l) __builtin_amdgcn_global_load_lds( \
    (const __attribute__((address_space(1))) void*)(g),     \
    (__attribute__((address_space(3))) void*)(l), 16, 0, 0)

__device__ __forceinline__ u16 f2bf(float f) {
    u32 u = __float_as_uint(f);
    return (u16)((u + 0x7FFFu + ((u >> 16) & 1u)) >> 16);
}

__device__ __forceinline__ float ssp_f(float x) {
    // softplus(x) - ln2 = ln(0.5*(exp(x)+1)); x here is O(1-10), no overflow risk
    return __logf(0.5f * (__expf(x) + 1.0f));
}

__device__ __forceinline__ float ssp_slow(float x) {
    return fmaxf(x, 0.0f) + log1pf(expf(-fabsf(x))) - 0.6931471805599453f;
}

// ---------------- conversions ----------------

__global__ __launch_bounds__(256) void conv_a(const float* __restrict__ in,
                                              u16* __restrict__ out) {
    int i = (blockIdx.x * 256 + threadIdx.x) * 8;
    float4 x = *(const float4*)(in + i);
    float4 y = *(const float4*)(in + i + 4);
    union { u16 h[8]; uint4 v; } o;
    o.h[0] = f2bf(x.x); o.h[1] = f2bf(x.y); o.h[2] = f2bf(x.z); o.h[3] = f2bf(x.w);
    o.h[4] = f2bf(y.x); o.h[5] = f2bf(y.y); o.h[6] = f2bf(y.z); o.h[7] = f2bf(y.w);
    *(uint4*)(out + i) = o.v;
}

__global__ __launch_bounds__(256) void conv_w(const float* __restrict__ W1,
                                              const float* __restrict__ Wc1,
                                              u16* __restrict__ Bt) {
    __shared__ float tile[32][33];
    const int k0 = blockIdx.x * 32;
    const int n0 = blockIdx.y * 32;                 // 0..1023
    const float* src = (n0 < 512) ? W1 : Wc1;
    const int ns0 = (n0 < 512) ? n0 : n0 - 512;
    const int t = threadIdx.x;
#pragma unroll
    for (int j = 0; j < 4; j++) {
        int idx = j * 256 + t;
        int kl = idx >> 5, nl = idx & 31;
        tile[kl][nl] = src[(size_t)(k0 + kl) * 512 + ns0 + nl];
    }
    __syncthreads();
#pragma unroll
    for (int j = 0; j < 4; j++) {
        int idx = j * 256 + t;
        int nl = idx >> 5, kl = idx & 31;
        Bt[(size_t)(n0 + nl) * 1024 + k0 + kl] = f2bf(tile[kl][nl]);
    }
}

// ---------------- bf16 MFMA GEMM ----------------
// Tile 128(M) x 128(N), BK=32. 4 waves in 2x2; each wave 4x4 tiles of 16x16.
// LDS: As/Bs [row 0..127][k8slot 0..3] of 8-bf16 chunks, slot = k8 ^ ((row>>2)&3).

__global__ __launch_bounds__(256) void gemm_mfma(
    const u16* __restrict__ A,    // [16384,1024] bf16
    const u16* __restrict__ Bt,   // [1024(n),1024(k)] bf16
    const float* __restrict__ b1, const float* __restrict__ W2,
    const float* __restrict__ bc1, const float* __restrict__ Wc2,
    float* __restrict__ yi_part, float* __restrict__ q_part)
{
    __shared__ u16 As[128 * 32];
    __shared__ u16 Bs[128 * 32];
    const int bm = blockIdx.x;          // 128
    const int bn = blockIdx.y;          // 8
    const int tid = threadIdx.x;
    const int w = tid >> 6, lane = tid & 63;
    const int wave_m = w & 1, wave_n = w >> 1;
    const int lm = lane & 15, q = lane >> 4;

    f32x4 acc[4][4];
#pragma unroll
    for (int i = 0; i < 4; i++)
#pragma unroll
        for (int j = 0; j < 4; j++)
            acc[i][j] = (f32x4){0.0f, 0.0f, 0.0f, 0.0f};

    const size_t a_base = (size_t)(bm * 128) * GK;
    const size_t b_base = (size_t)(bn * 128) * GK;

    // staging geometry: instruction (w,p) covers chunks [(w*2+p)*64, +64)
    int goff[2];
#pragma unroll
    for (int p = 0; p < 2; p++) {
        int c = (w * 2 + p) * 64 + lane;
        int row = c >> 2;
        int slot = c & 3;
        int k8 = slot ^ ((row >> 2) & 3);
        goff[p] = row * GK + k8 * 8;
    }

    // frag read offsets (elements), constant over kt
    int aoff[4], boff[4];
#pragma unroll
    for (int i = 0; i < 4; i++) {
        int mrow = wave_m * 64 + i * 16 + lm;
        aoff[i] = mrow * 32 + (q ^ ((mrow >> 2) & 3)) * 8;
        int nrow = wave_n * 64 + i * 16 + lm;
        boff[i] = nrow * 32 + (q ^ ((nrow >> 2) & 3)) * 8;
    }

    for (int kt = 0; kt < GK; kt += 32) {
#pragma unroll
        for (int p = 0; p < 2; p++) {
            GLOAD_LDS16(A + a_base + kt + goff[p], &As[(w * 2 + p) << 9]);
            GLOAD_LDS16(Bt + b_base + kt + goff[p], &Bs[(w * 2 + p) << 9]);
        }
        __syncthreads();
        bf16x8 af[4], bfr[4];
#pragma unroll
        for (int i = 0; i < 4; i++) {
            af[i] = *(const bf16x8*)&As[aoff[i]];
            bfr[i] = *(const bf16x8*)&Bs[boff[i]];
        }
#pragma unroll
        for (int i = 0; i < 4; i++)
#pragma unroll
            for (int j = 0; j < 4; j++)
                acc[i][j] = __builtin_amdgcn_mfma_f32_16x16x32_bf16(af[i], bfr[j],
                                                                    acc[i][j], 0, 0, 0);
        __syncthreads();
    }

    // epilogue: per row sum_n v[n]*ssp(c+bias[n]), reduce over 16 col-lanes
    const bool is_q = (bn >= 4);
    const float* bb = is_q ? bc1 : b1;
    const float* vv = is_q ? Wc2 : W2;
    float* target = is_q ? q_part : yi_part;
    const int cb0 = (bn & 3) * 128 + wave_n * 64;
    float bias[4], v[4];
#pragma unroll
    for (int j = 0; j < 4; j++) {
        int c = cb0 + j * 16 + lm;
        bias[j] = bb[c];
        v[j] = vv[c];
    }
    const int rowg0 = bm * 128 + wave_m * 64;
#pragma unroll
    for (int i = 0; i < 4; i++) {
#pragma unroll
        for (int r = 0; r < 4; r++) {
            float s = 0.0f;
#pragma unroll
            for (int j = 0; j < 4; j++)
                s += v[j] * ssp_f(acc[i][j][r] + bias[j]);
            s += __shfl_xor(s, 1);
            s += __shfl_xor(s, 2);
            s += __shfl_xor(s, 4);
            s += __shfl_xor(s, 8);
            if (lm == 0) atomicAdd(&target[rowg0 + i * 16 + q * 4 + r], s);
        }
    }
}

// ---------------- coulomb (unchanged from R1) ----------------

__global__ __launch_bounds__(256) void coulomb_k(
    const float* __restrict__ R, const float* __restrict__ mask,
    const float* __restrict__ yi_part, const float* __restrict__ q_part,
    const float* __restrict__ b2p, const float* __restrict__ bc2p,
    float* __restrict__ out)
{
    const int N = 512;
    const int b = blockIdx.y;
    const int chunk = blockIdx.x;
    __shared__ float Rx[512], Ry[512], Rz[512], QM[512];
    __shared__ float rbuf[4];
    const int tid = threadIdx.x;
    const float bc2 = bc2p[0];
    const float b2 = b2p[0];

    for (int j = tid; j < N; j += 256) {
        float m = mask[b * N + j];
        const float* rp = R + ((size_t)b * N + j) * 3;
        Rx[j] = rp[0];
        Ry[j] = rp[1];
        Rz[j] = rp[2];
        QM[j] = (q_part[b * N + j] + bc2) * m;
    }
    __syncthreads();

    const int i = chunk * 64 + (tid & 63);
    const int js = (tid >> 6) * 128;
    const float xi = Rx[i], yi = Ry[i], zi = Rz[i], qmi = QM[i];
    float e = 0.0f;
    for (int j = js; j < js + 128; j++) {
        float dx = xi - Rx[j];
        float dy = yi - Ry[j];
        float dz = zi - Rz[j];
        float d2 = dx * dx + dy * dy + dz * dz;
        float dist = sqrtf(d2);
        float t = 1e-5f + dist;
        float term = qmi * QM[j] / (t * t);
        e += (j == i) ? 0.0f : term;
    }
    if (tid < 64) {
        int ii = chunk * 64 + tid;
        e += (yi_part[b * N + ii] + b2) * mask[b * N + ii];
    }
    for (int off = 32; off > 0; off >>= 1) e += __shfl_down(e, off, 64);
    if ((tid & 63) == 0) rbuf[tid >> 6] = e;
    __syncthreads();
    if (tid == 0) atomicAdd(&out[b], rbuf[0] + rbuf[1] + rbuf[2] + rbuf[3]);
}

// ---------------- fp32 fallback GEMM (R1 kernel, used only if ws too small) ----

#define BM 128
#define BN 64
#define BK 16

__global__ __launch_bounds__(256) void mlp_gemm(
    const float* __restrict__ A, const float* __restrict__ W1,
    const float* __restrict__ Wc1, const float* __restrict__ b1,
    const float* __restrict__ bc1, const float* __restrict__ W2,
    const float* __restrict__ Wc2, float* __restrict__ yi_part,
    float* __restrict__ q_part)
{
    const int K = 1024;
    const int bm = blockIdx.x;
    const int bn = blockIdx.y;
    const bool is_q = (bn >= 8);
    const float* __restrict__ W = is_q ? Wc1 : W1;
    const int j0 = (bn & 7) * BN;

    __shared__ float As[BK][BM + 4];
    __shared__ float Bs[BK][BN + 4];
    __shared__ float red[BM];

    const int tid = threadIdx.x;
    const int tx = tid & 15;
    const int ty = tid >> 4;

    float acc[8][4];
#pragma unroll
    for (int r = 0; r < 8; r++)
#pragma unroll
        for (int c = 0; c < 4; c++) acc[r][c] = 0.0f;

    const int a_row = tid >> 2;
    const int a_k4 = (tid & 3) * 4;
    const float* Arow0 = A + (size_t)(bm * BM + a_row) * K;
    const float* Arow1 = Arow0 + (size_t)64 * K;
    const int w_k = tid >> 4;
    const int w_j = (tid & 15) * 4;

    for (int kt = 0; kt < K; kt += BK) {
        float4 av0 = *(const float4*)(Arow0 + kt + a_k4);
        float4 av1 = *(const float4*)(Arow1 + kt + a_k4);
        float4 wv = *(const float4*)(W + (size_t)(kt + w_k) * 512 + j0 + w_j);
        __syncthreads();
        As[a_k4 + 0][a_row] = av0.x;
        As[a_k4 + 1][a_row] = av0.y;
        As[a_k4 + 2][a_row] = av0.z;
        As[a_k4 + 3][a_row] = av0.w;
        As[a_k4 + 0][a_row + 64] = av1.x;
        As[a_k4 + 1][a_row + 64] = av1.y;
        As[a_k4 + 2][a_row + 64] = av1.z;
        As[a_k4 + 3][a_row + 64] = av1.w;
        *(float4*)&Bs[w_k][w_j] = wv;
        __syncthreads();
#pragma unroll
        for (int kk = 0; kk < BK; kk++) {
            float4 a0 = *(const float4*)&As[kk][ty * 8];
            float4 a1 = *(const float4*)&As[kk][ty * 8 + 4];
            float4 bv = *(const float4*)&Bs[kk][tx * 4];
            float ar[8] = {a0.x, a0.y, a0.z, a0.w, a1.x, a1.y, a1.z, a1.w};
            float bc[4] = {bv.x, bv.y, bv.z, bv.w};
#pragma unroll
            for (int r = 0; r < 8; r++)
#pragma unroll
                for (int c = 0; c < 4; c++)
                    acc[r][c] = fmaf(ar[r], bc[c], acc[r][c]);
        }
    }

    const float* bb = is_q ? bc1 : b1;
    const float* vv = is_q ? Wc2 : W2;
    float bias[4], v[4];
#pragma unroll
    for (int c = 0; c < 4; c++) {
        bias[c] = bb[j0 + tx * 4 + c];
        v[c] = vv[j0 + tx * 4 + c];
    }
    if (tid < BM) red[tid] = 0.0f;
    __syncthreads();
#pragma unroll
    for (int r = 0; r < 8; r++) {
        float s = 0.0f;
#pragma unroll
        for (int c = 0; c < 4; c++)
            s += v[c] * ssp_slow(acc[r][c] + bias[c]);
        atomicAdd(&red[ty * 8 + r], s);
    }
    __syncthreads();
    float* target = is_q ? q_part : yi_part;
    if (tid < BM) atomicAdd(&target[(size_t)bm * BM + tid], red[tid]);
}

// ---------------- launch ----------------

extern "C" void kernel_launch(void* const* d_in, const int* in_sizes, int n_in,
                              void* d_out, int out_size, void* d_ws, size_t ws_size,
                              hipStream_t stream) {
    const float* rep  = (const float*)d_in[0];
    const float* R    = (const float*)d_in[1];
    const float* mask = (const float*)d_in[2];
    const float* W1   = (const float*)d_in[3];
    const float* b1   = (const float*)d_in[4];
    const float* W2   = (const float*)d_in[5];
    const float* b2   = (const float*)d_in[6];
    const float* Wc1  = (const float*)d_in[7];
    const float* bc1  = (const float*)d_in[8];
    const float* Wc2  = (const float*)d_in[9];
    const float* bc2  = (const float*)d_in[10];
    float* out = (float*)d_out;

    const size_t szA = 16384ull * 1024 * 2;   // 32 MB bf16 A
    const size_t szB = 1024ull * 1024 * 2;    // 2 MB bf16 Bt
    const size_t need = szA + szB + 2 * 16384 * sizeof(float);

    if (ws_size >= need) {
        u16* Abf = (u16*)d_ws;
        u16* Btb = (u16*)((char*)d_ws + szA);
        float* yi_part = (float*)((char*)d_ws + szA + szB);
        float* q_part = yi_part + 16384;

        hipMemsetAsync(yi_part, 0, 2 * 16384 * sizeof(float), stream);
        hipMemsetAsync(d_out, 0, 32 * sizeof(float), stream);

        conv_a<<<8192, 256, 0, stream>>>(rep, Abf);
        conv_w<<<dim3(32, 32), 256, 0, stream>>>(W1, Wc1, Btb);
        gemm_mfma<<<dim3(128, 8), 256, 0, stream>>>(Abf, Btb, b1, W2, bc1, Wc2,
                                                    yi_part, q_part);
        coulomb_k<<<dim3(8, 32), 256, 0, stream>>>(R, mask, yi_part, q_part, b2, bc2, out);
    } else {
        float* yi_part = (float*)d_ws;
        float* q_part = yi_part + 16384;
        hipMemsetAsync(d_ws, 0, 2 * 16384 * sizeof(float), stream);
        hipMemsetAsync(d_out, 0, 32 * sizeof(float), stream);
        mlp_gemm<<<dim3(128, 16), 256, 0, stream>>>(rep, W1, Wc1, b1, bc1, W2, Wc2,
                                                    yi_part, q_part);
        coulomb_k<<<dim3(8, 32), 256, 0, stream>>>(R, mask, yi_part, q_part, b2, bc2, out);
    }
}